// Round 3
// baseline (996.380 us; speedup 1.0000x reference)
//
#include <hip/hip_runtime.h>
#include <hip/hip_cooperative_groups.h>
#include <stdint.h>

namespace cg = cooperative_groups;

// ---------------------------------------------------------------------------
// CascadeGaussianAdapter: sequential multi-view redundancy removal.
// d_out layout (floats), N = v*hw slots:
//   O0 = 0   : means  (N,3) | O1 = 3N : covs (N,9) | O2 = 12N : sh (N,75)
//   O3 = 87N : opa (N)      | O4 = 88N: scales (N,3)| O5 = 91N : rots (N,4)
//   O6 = 95N : valid (N)
//
// Single cooperative kernel (grid=1024 blocks, 4/CU co-resident):
//   phase 0            : zero bitmap regions 1..v-1
//   phase p (1..v-1)   : blocks [0,G/8) mark view p  ||  blocks [G/8,G) copy
//                        view p-1's output slice (view-0 copy is maskless)
//   phase v            : all blocks copy view v-1's slice
// grid.sync() between phases replaces kernel boundaries (removes 3 launch
// gaps + 1 dispatch). __threadfence() before each sync publishes the
// non-atomic bitmap byte stores across XCDs.
// The FP64 inv4x4 lives in a separate 1-block pre-kernel so its register
// spike doesn't cap the fused kernel's occupancy (cooperative launch needs
// 4 blocks/CU => VGPR <= 128, enforced by __launch_bounds__(256,4)).
// d_ws: [0,1024) w2c matrices (v*16 f), [1024, 1024+v*hw) occlusion bitmaps
// (region 0 is never read or written).
// ---------------------------------------------------------------------------

// Native 16B vector type: __builtin_nontemporal_* rejects HIP_vector_type.
typedef float f4 __attribute__((ext_vector_type(4)));

__device__ void inv4x4(const float* M, float* out) {
    double m[16];
    for (int i = 0; i < 16; ++i) m[i] = (double)M[i];
    double inv[16];
    inv[0]  =  m[5]*m[10]*m[15] - m[5]*m[11]*m[14] - m[9]*m[6]*m[15] + m[9]*m[7]*m[14] + m[13]*m[6]*m[11] - m[13]*m[7]*m[10];
    inv[4]  = -m[4]*m[10]*m[15] + m[4]*m[11]*m[14] + m[8]*m[6]*m[15] - m[8]*m[7]*m[14] - m[12]*m[6]*m[11] + m[12]*m[7]*m[10];
    inv[8]  =  m[4]*m[9]*m[15]  - m[4]*m[11]*m[13] - m[8]*m[5]*m[15] + m[8]*m[7]*m[13] + m[12]*m[5]*m[11] - m[12]*m[7]*m[9];
    inv[12] = -m[4]*m[9]*m[14]  + m[4]*m[10]*m[13] + m[8]*m[5]*m[14] - m[8]*m[6]*m[13] - m[12]*m[5]*m[10] + m[12]*m[6]*m[9];
    inv[1]  = -m[1]*m[10]*m[15] + m[1]*m[11]*m[14] + m[9]*m[2]*m[15] - m[9]*m[3]*m[14] - m[13]*m[2]*m[11] + m[13]*m[3]*m[10];
    inv[5]  =  m[0]*m[10]*m[15] - m[0]*m[11]*m[14] - m[8]*m[2]*m[15] + m[8]*m[3]*m[14] + m[12]*m[2]*m[11] - m[12]*m[3]*m[10];
    inv[9]  = -m[0]*m[9]*m[15]  + m[0]*m[11]*m[13] + m[8]*m[1]*m[15] - m[8]*m[3]*m[13] - m[12]*m[1]*m[11] + m[12]*m[3]*m[9];
    inv[13] =  m[0]*m[9]*m[14]  - m[0]*m[10]*m[13] - m[8]*m[1]*m[14] + m[8]*m[2]*m[13] + m[12]*m[1]*m[10] - m[12]*m[2]*m[9];
    inv[2]  =  m[1]*m[6]*m[15]  - m[1]*m[7]*m[14]  - m[5]*m[2]*m[15] + m[5]*m[3]*m[14] + m[13]*m[2]*m[7]  - m[13]*m[3]*m[6];
    inv[6]  = -m[0]*m[6]*m[15]  + m[0]*m[7]*m[14]  + m[4]*m[2]*m[15] - m[4]*m[3]*m[14] - m[12]*m[2]*m[7]  + m[12]*m[3]*m[6];
    inv[10] =  m[0]*m[5]*m[15]  - m[0]*m[7]*m[13]  - m[4]*m[1]*m[15] + m[4]*m[3]*m[13] + m[12]*m[1]*m[7]  - m[12]*m[3]*m[5];
    inv[14] = -m[0]*m[5]*m[14]  + m[0]*m[6]*m[13]  + m[4]*m[1]*m[14] - m[4]*m[2]*m[13] - m[12]*m[1]*m[6]  + m[12]*m[2]*m[5];
    inv[3]  = -m[1]*m[6]*m[11]  + m[1]*m[7]*m[10]  + m[5]*m[2]*m[11] - m[5]*m[3]*m[10] - m[9]*m[2]*m[7]   + m[9]*m[3]*m[6];
    inv[7]  =  m[0]*m[6]*m[11]  - m[0]*m[7]*m[10]  - m[4]*m[2]*m[11] + m[4]*m[3]*m[10] + m[8]*m[2]*m[7]   - m[8]*m[3]*m[6];
    inv[11] = -m[0]*m[5]*m[11]  + m[0]*m[7]*m[9]   + m[4]*m[1]*m[11] - m[4]*m[3]*m[9]  - m[8]*m[1]*m[7]   + m[8]*m[3]*m[5];
    inv[15] =  m[0]*m[5]*m[10]  - m[0]*m[6]*m[9]   - m[4]*m[1]*m[10] + m[4]*m[2]*m[9]  + m[8]*m[1]*m[6]   - m[8]*m[2]*m[5];
    double det = m[0]*inv[0] + m[1]*inv[4] + m[2]*inv[8] + m[3]*inv[12];
    double idet = 1.0 / det;
    for (int i = 0; i < 16; ++i) out[i] = (float)(inv[i] * idet);
}

// Tiny pre-kernel: invert extrinsics for views 1..v-1 (w2c[0] never used).
__global__ void init_w2c(const float* __restrict__ extr, float* __restrict__ w2c, int v) {
    int t = (int)threadIdx.x;
    if (t >= 1 && t < v) inv4x4(extr + t * 16, w2c + t * 16);
}

struct Params {
    const float* means;                      // (v,hw,3) flat
    const f4* means4; const f4* covs4; const f4* shs4;
    const f4* opas4;  const f4* scales4; const f4* rots4;
    const float* w2c;                        // v*16
    const float* intr;                       // v*9
    const int* hp; const int* wp;
    uint8_t* bitmaps;                        // v*hw (region 0 unused)
    f4* out;
    int v, hw, n4;
};

// Masked stream-copy of view cv's output slice; bit-identical to the verified
// round-2 copy body.
__device__ __forceinline__ void copy_view(const Params& P, int cv, int start, int stride) {
    const int H4 = P.hw >> 2;
    const int b0 = 3 * H4,  b1 = 12 * H4, b2 = 87 * H4,
              b3 = 88 * H4, b4 = 91 * H4, b5 = 95 * H4, b6 = 96 * H4;
    const int n4 = P.n4;
    const uint8_t* bmc = (cv == 0) ? (const uint8_t*)nullptr : P.bitmaps + cv * P.hw;
    const bool has = (bmc != nullptr);
    for (int q = start; q < b6; q += stride) {
        f4 val;
        int oi;
        if (q < b0) {                                // means, s=3
            int t = q, e = 4 * t;
            val = __builtin_nontemporal_load(&P.means4[cv * b0 + t]);
            if (has) {
                if (bmc[(e + 0) / 3]) val.x = 0.f;
                if (bmc[(e + 1) / 3]) val.y = 0.f;
                if (bmc[(e + 2) / 3]) val.z = 0.f;
                if (bmc[(e + 3) / 3]) val.w = 0.f;
            }
            oi = cv * b0 + t;
        } else if (q < b1) {                         // covs, s=9
            int t = q - b0, e = 4 * t;
            val = __builtin_nontemporal_load(&P.covs4[cv * 9 * H4 + t]);
            if (has) {
                if (bmc[(e + 0) / 9]) val.x = 0.f;
                if (bmc[(e + 1) / 9]) val.y = 0.f;
                if (bmc[(e + 2) / 9]) val.z = 0.f;
                if (bmc[(e + 3) / 9]) val.w = 0.f;
            }
            oi = 3 * n4 + cv * 9 * H4 + t;
        } else if (q < b2) {                         // sh, s=75
            int t = q - b1, e = 4 * t;
            val = __builtin_nontemporal_load(&P.shs4[cv * 75 * H4 + t]);
            if (has) {
                if (bmc[(e + 0) / 75]) val.x = 0.f;
                if (bmc[(e + 1) / 75]) val.y = 0.f;
                if (bmc[(e + 2) / 75]) val.z = 0.f;
                if (bmc[(e + 3) / 75]) val.w = 0.f;
            }
            oi = 12 * n4 + cv * 75 * H4 + t;
        } else if (q < b3) {                         // opacity, s=1
            int t = q - b2, e = 4 * t;
            val = __builtin_nontemporal_load(&P.opas4[cv * H4 + t]);
            if (has) {
                if (bmc[e + 0]) val.x = 0.f;
                if (bmc[e + 1]) val.y = 0.f;
                if (bmc[e + 2]) val.z = 0.f;
                if (bmc[e + 3]) val.w = 0.f;
            }
            oi = 87 * n4 + cv * H4 + t;
        } else if (q < b4) {                         // scales, s=3
            int t = q - b3, e = 4 * t;
            val = __builtin_nontemporal_load(&P.scales4[cv * 3 * H4 + t]);
            if (has) {
                if (bmc[(e + 0) / 3]) val.x = 0.f;
                if (bmc[(e + 1) / 3]) val.y = 0.f;
                if (bmc[(e + 2) / 3]) val.z = 0.f;
                if (bmc[(e + 3) / 3]) val.w = 0.f;
            }
            oi = 88 * n4 + cv * 3 * H4 + t;
        } else if (q < b5) {                         // rots, s=4 -> one point/f4
            int t = q - b4;
            val = __builtin_nontemporal_load(&P.rots4[cv * 4 * H4 + t]);
            if (has && bmc[t]) { val.x = 0.f; val.y = 0.f; val.z = 0.f; val.w = 0.f; }
            oi = 91 * n4 + cv * 4 * H4 + t;
        } else {                                     // valid, s=1
            int t = q - b5, e = 4 * t;
            if (has) {
                val.x = bmc[e + 0] ? 0.f : 1.f;
                val.y = bmc[e + 1] ? 0.f : 1.f;
                val.z = bmc[e + 2] ? 0.f : 1.f;
                val.w = bmc[e + 3] ? 0.f : 1.f;
            } else {
                val.x = 1.f; val.y = 1.f; val.z = 1.f; val.w = 1.f;
            }
            oi = 95 * n4 + cv * H4 + t;
        }
        __builtin_nontemporal_store(val, &P.out[oi]);
    }
}

__global__ void __launch_bounds__(256, 4) fused(Params P) {
#pragma clang fp contract(off)
    cg::grid_group grid = cg::this_grid();
    const int hw  = P.hw;
    const int G   = (int)gridDim.x;
    const int bid = (int)blockIdx.x;
    const int tid = (int)threadIdx.x;
    const int lin = bid * 256 + tid;
    const int MB  = G >> 3;                  // marking blocks per phase

    // ---- phase 0: zero bitmap regions 1..v-1 ----
    {
        uint32_t* zw = (uint32_t*)(P.bitmaps + hw);
        const int n_words = (P.v - 1) * (hw >> 2);
        for (int i = lin; i < n_words; i += G * 256) zw[i] = 0u;
    }
    __threadfence();
    grid.sync();

    const int w_ = *P.wp;
    const int h_ = *P.hp;

    // ---- phases 1..v-1: mark view p || copy view p-1 ----
    for (int p = 1; p < P.v; ++p) {
        if (bid < MB) {
            const float* w2c  = P.w2c + p * 16;
            const float* intr = P.intr + p * 9;
            uint8_t* bmout = P.bitmaps + p * hw;
            const float* mv = P.means + p * hw * 3;
            const int n_prev = p * hw;
            const float a0 = w2c[0], a1 = w2c[1], a2 = w2c[2],  a3  = w2c[3];
            const float a4 = w2c[4], a5 = w2c[5], a6 = w2c[6],  a7  = w2c[7];
            const float a8 = w2c[8], a9 = w2c[9], a10 = w2c[10], a11 = w2c[11];
            const float i0 = intr[0], i1 = intr[1], i2 = intr[2];
            const float i3 = intr[3], i4 = intr[4], i5 = intr[5];
            for (int i = bid * 256 + tid; i < n_prev; i += MB * 256) {
                // view-0 candidates (i < hw) always valid; others check keep-bit
                if (i >= hw && P.bitmaps[i] != 0) continue;
                float px = P.means[3 * i + 0];
                float py = P.means[3 * i + 1];
                float pz = P.means[3 * i + 2];
                float c0 = a0 * px + a1 * py + a2  * pz + a3;
                float c1 = a4 * px + a5 * py + a6  * pz + a7;
                float c2 = a8 * px + a9 * py + a10 * pz + a11;
                bool vz = c2 > 1e-8f;
                float zz = fmaxf(c2, 1e-8f);
                float xp = c0 / zz;
                float yp = c1 / zz;
                float n0 = (xp * i0 + yp * i1) + i2;
                float n1 = (xp * i3 + yp * i4) + i5;
                bool m = (n0 >= 0.0f) & (n0 < 1.0f) & (n1 >= 0.0f) & (n1 < 1.0f) & vz;
                if (!m) continue;
                int x = (int)floorf(n0 * (float)w_);
                int y = (int)floorf(n1 * (float)h_);
                int pix = y * h_ + x;        // reference uses h here, not w
                pix = min(max(pix, 0), hw - 1);
                float dx = px - mv[3 * pix + 0];
                float dy = py - mv[3 * pix + 1];
                float dz = pz - mv[3 * pix + 2];
                float dist = sqrtf((dx * dx + dy * dy) + dz * dz);
                if (dist <= 0.2f) bmout[pix] = 1;   // benign race: all store 1
            }
        } else {
            copy_view(P, p - 1, (bid - MB) * 256 + tid, (G - MB) * 256);
        }
        __threadfence();
        grid.sync();
    }

    // ---- final phase: copy last view's slice with all blocks ----
    copy_view(P, P.v - 1, lin, G * 256);
}

extern "C" void kernel_launch(void* const* d_in, const int* in_sizes, int n_in,
                              void* d_out, int out_size, void* d_ws, size_t ws_size,
                              hipStream_t stream) {
    const float* means  = (const float*)d_in[0];
    const float* covs   = (const float*)d_in[1];
    const float* shs    = (const float*)d_in[2];
    const float* opas   = (const float*)d_in[3];
    const float* scales = (const float*)d_in[4];
    const float* rots   = (const float*)d_in[5];
    const float* extr   = (const float*)d_in[6];
    const float* intr   = (const float*)d_in[7];
    const int*   hp     = (const int*)d_in[8];
    const int*   wp     = (const int*)d_in[9];

    const int v  = in_sizes[6] / 16;      // b*v, b==1 here
    const int hw = in_sizes[3] / v;
    const long N = (long)v * hw;

    float*   w2c     = (float*)d_ws;                 // v*16 floats
    uint8_t* bitmaps = (uint8_t*)d_ws + 1024;        // v*hw bytes (region 0 unused)

    init_w2c<<<1, 64, 0, stream>>>(extr, w2c, v);

    Params P;
    P.means   = means;
    P.means4  = (const f4*)means;
    P.covs4   = (const f4*)covs;
    P.shs4    = (const f4*)shs;
    P.opas4   = (const f4*)opas;
    P.scales4 = (const f4*)scales;
    P.rots4   = (const f4*)rots;
    P.w2c     = w2c;
    P.intr    = intr;
    P.hp      = hp;
    P.wp      = wp;
    P.bitmaps = bitmaps;
    P.out     = (f4*)d_out;
    P.v       = v;
    P.hw      = hw;
    P.n4      = (int)(N >> 2);

    void* args[] = { &P };
    hipLaunchCooperativeKernel((const void*)fused, dim3(1024), dim3(256),
                               args, 0, stream);
}

// Round 4
// 199.521 us; speedup vs baseline: 4.9939x; 4.9939x over previous
//
#include <hip/hip_runtime.h>
#include <stdint.h>

// ---------------------------------------------------------------------------
// CascadeGaussianAdapter: sequential multi-view redundancy removal.
// d_out layout (floats), N = v*hw slots:
//   O0 = 0   : means  (N,3) | O1 = 3N : covs (N,9) | O2 = 12N : sh (N,75)
//   O3 = 87N : opa (N)      | O4 = 88N: scales (N,3)| O5 = 91N : rots (N,4)
//   O6 = 95N : valid (N)
//
// Pipeline (v=4), VERIFIED at 197.8 us (round 2):
//   A: init            — zero bitmap regions 1..v-1, compute w2c[1..v-1]
//   B: mark1 + copy v0 — view-1 marking (view-0 points always valid, no bitmap
//                        load) overlapped with mask-free copy of view-0 slice
//   C: mark2 + copy v1 — view-2 marking || masked copy of view-1 slice
//   D: mark3 + copy v2 — view-3 marking || masked copy of view-2 slice
//   E:         copy v3 — masked copy of view-3 slice
// Marking is latency-bound (random gathers/scatters); co-resident copy blocks
// keep HBM saturated so the serial mark chain costs ~0 extra time. Mark
// blocks are FIRST in the grid so their latency chains start at dispatch.
// NOTE (round 3 post-mortem): do NOT fuse these into one cooperative kernel —
// cg::grid_group::sync() on gfx950 costs ~160 us/sync (measured 850 us total,
// VALUBusy 1.1%), vastly worse than the ~2 us inter-dispatch gaps.
// d_ws: [0,1024) w2c matrices (v*16 f), [1024, 1024+v*hw) occlusion bitmaps
// (region 0 is never read or written).
// ---------------------------------------------------------------------------

// Native 16B vector type: __builtin_nontemporal_* rejects HIP_vector_type.
typedef float f4 __attribute__((ext_vector_type(4)));

__device__ void inv4x4(const float* M, float* out) {
    double m[16];
    for (int i = 0; i < 16; ++i) m[i] = (double)M[i];
    double inv[16];
    inv[0]  =  m[5]*m[10]*m[15] - m[5]*m[11]*m[14] - m[9]*m[6]*m[15] + m[9]*m[7]*m[14] + m[13]*m[6]*m[11] - m[13]*m[7]*m[10];
    inv[4]  = -m[4]*m[10]*m[15] + m[4]*m[11]*m[14] + m[8]*m[6]*m[15] - m[8]*m[7]*m[14] - m[12]*m[6]*m[11] + m[12]*m[7]*m[10];
    inv[8]  =  m[4]*m[9]*m[15]  - m[4]*m[11]*m[13] - m[8]*m[5]*m[15] + m[8]*m[7]*m[13] + m[12]*m[5]*m[11] - m[12]*m[7]*m[9];
    inv[12] = -m[4]*m[9]*m[14]  + m[4]*m[10]*m[13] + m[8]*m[5]*m[14] - m[8]*m[6]*m[13] - m[12]*m[5]*m[10] + m[12]*m[6]*m[9];
    inv[1]  = -m[1]*m[10]*m[15] + m[1]*m[11]*m[14] + m[9]*m[2]*m[15] - m[9]*m[3]*m[14] - m[13]*m[2]*m[11] + m[13]*m[3]*m[10];
    inv[5]  =  m[0]*m[10]*m[15] - m[0]*m[11]*m[14] - m[8]*m[2]*m[15] + m[8]*m[3]*m[14] + m[12]*m[2]*m[11] - m[12]*m[3]*m[10];
    inv[9]  = -m[0]*m[9]*m[15]  + m[0]*m[11]*m[13] + m[8]*m[1]*m[15] - m[8]*m[3]*m[13] - m[12]*m[1]*m[11] + m[12]*m[3]*m[9];
    inv[13] =  m[0]*m[9]*m[14]  - m[0]*m[10]*m[13] - m[8]*m[1]*m[14] + m[8]*m[2]*m[13] + m[12]*m[1]*m[10] - m[12]*m[2]*m[9];
    inv[2]  =  m[1]*m[6]*m[15]  - m[1]*m[7]*m[14]  - m[5]*m[2]*m[15] + m[5]*m[3]*m[14] + m[13]*m[2]*m[7]  - m[13]*m[3]*m[6];
    inv[6]  = -m[0]*m[6]*m[15]  + m[0]*m[7]*m[14]  + m[4]*m[2]*m[15] - m[4]*m[3]*m[14] - m[12]*m[2]*m[7]  + m[12]*m[3]*m[6];
    inv[10] =  m[0]*m[5]*m[15]  - m[0]*m[7]*m[13]  - m[4]*m[1]*m[15] + m[4]*m[3]*m[13] + m[12]*m[1]*m[7]  - m[12]*m[3]*m[5];
    inv[14] = -m[0]*m[5]*m[14]  + m[0]*m[6]*m[13]  + m[4]*m[1]*m[14] - m[4]*m[2]*m[13] - m[12]*m[1]*m[6]  + m[12]*m[2]*m[5];
    inv[3]  = -m[1]*m[6]*m[11]  + m[1]*m[7]*m[10]  + m[5]*m[2]*m[11] - m[5]*m[3]*m[10] - m[9]*m[2]*m[7]   + m[9]*m[3]*m[6];
    inv[7]  =  m[0]*m[6]*m[11]  - m[0]*m[7]*m[10]  - m[4]*m[2]*m[11] + m[4]*m[3]*m[10] + m[8]*m[2]*m[7]   - m[8]*m[3]*m[6];
    inv[11] = -m[0]*m[5]*m[11]  + m[0]*m[7]*m[9]   + m[4]*m[1]*m[11] - m[4]*m[3]*m[9]  - m[8]*m[1]*m[7]   + m[8]*m[3]*m[5];
    inv[15] =  m[0]*m[5]*m[10]  - m[0]*m[6]*m[9]   - m[4]*m[1]*m[10] + m[4]*m[2]*m[9]  + m[8]*m[1]*m[6]   - m[8]*m[2]*m[5];
    double det = m[0]*inv[0] + m[1]*inv[4] + m[2]*inv[8] + m[3]*inv[12];
    double idet = 1.0 / det;
    for (int i = 0; i < 16; ++i) out[i] = (float)(inv[i] * idet);
}

// Zero bitmap regions 1..v-1 (region 0 is never read) + invert extrinsics for
// views 1..v-1 (w2c[0] is never used).
__global__ void init_kernel(const float* __restrict__ extr, float* __restrict__ w2c,
                            uint32_t* __restrict__ zero_words, int v, int n_words) {
    int tid = blockIdx.x * blockDim.x + threadIdx.x;
    int stride = gridDim.x * blockDim.x;
    for (int i = tid; i < n_words; i += stride) zero_words[i] = 0u;
    if (tid >= 1 && tid < v) inv4x4(extr + tid * 16, w2c + tid * 16);
}

// Role-split kernel: blocks [0, mark_blocks) mark view `k` occlusions; the
// remaining blocks stream-copy view `cview`'s finished output slice.
__global__ void __launch_bounds__(256) mark_copy(
        const float* __restrict__ means_all,    // input means (v,hw,3) flat
        const uint8_t* __restrict__ bm_all,     // bitmap base (v*hw bytes)
        const float* __restrict__ means_view,   // marking view's means (hw,3)
        const float* __restrict__ w2c,          // 16 floats (marking view)
        const float* __restrict__ intr,         // 9 floats  (marking view)
        uint8_t* __restrict__ bitmap_out,       // bitmap region of marking view
        int n_prev, const int* __restrict__ hp, const int* __restrict__ wp,
        int hw, int mark_blocks,
        const f4* __restrict__ means4, const f4* __restrict__ covs4,
        const f4* __restrict__ shs4,   const f4* __restrict__ opas4,
        const f4* __restrict__ scales4,const f4* __restrict__ rots4,
        const uint8_t* __restrict__ bmc,        // copy-view bitmap, null => keep all
        f4* __restrict__ out, int cview, int n4 /* (v*hw)/4 */) {
#pragma clang fp contract(off)
    if ((int)blockIdx.x < mark_blocks) {
        // ------------------- marking role (latency-bound) -------------------
        int i = (int)blockIdx.x * 256 + (int)threadIdx.x;
        if (i >= n_prev) return;
        // view-0 candidates (i < hw) are always valid; others check keep-bit
        if (i >= hw && bm_all[i] != 0) return;
        float px = means_all[3 * i + 0];
        float py = means_all[3 * i + 1];
        float pz = means_all[3 * i + 2];
        float c0 = w2c[0] * px + w2c[1] * py + w2c[2]  * pz + w2c[3];
        float c1 = w2c[4] * px + w2c[5] * py + w2c[6]  * pz + w2c[7];
        float c2 = w2c[8] * px + w2c[9] * py + w2c[10] * pz + w2c[11];
        bool vz = c2 > 1e-8f;
        float zz = fmaxf(c2, 1e-8f);
        float xp = c0 / zz;
        float yp = c1 / zz;
        float n0 = (xp * intr[0] + yp * intr[1]) + intr[2];
        float n1 = (xp * intr[3] + yp * intr[4]) + intr[5];
        bool m = (n0 >= 0.0f) & (n0 < 1.0f) & (n1 >= 0.0f) & (n1 < 1.0f) & vz;
        if (!m) return;
        int w_ = *wp;
        int h_ = *hp;
        int x = (int)floorf(n0 * (float)w_);
        int y = (int)floorf(n1 * (float)h_);
        int pix = y * h_ + x;            // reference uses h here, not w
        pix = min(max(pix, 0), hw - 1);
        float vx = means_view[3 * pix + 0];
        float vy = means_view[3 * pix + 1];
        float vw = means_view[3 * pix + 2];
        float dx = px - vx, dy = py - vy, dz = pz - vw;
        float dist = sqrtf((dx * dx + dy * dy) + dz * dz);
        if (dist <= 0.2f) bitmap_out[pix] = 1;   // benign race: all store 1
        return;
    }
    // --------------------- copy role (bandwidth-bound) ----------------------
    int q = ((int)blockIdx.x - mark_blocks) * 256 + (int)threadIdx.x;
    const int H4 = hw >> 2;                      // float4 per unit-region/view
    const int b0 = 3 * H4,  b1 = 12 * H4, b2 = 87 * H4,
              b3 = 88 * H4, b4 = 91 * H4, b5 = 95 * H4, b6 = 96 * H4;
    if (q >= b6) return;
    const bool has = (bmc != nullptr);
    f4 val;
    int oi;
    if (q < b0) {                                // means, s=3
        int t = q, e = 4 * t;
        val = __builtin_nontemporal_load(&means4[cview * b0 + t]);
        if (has) {
            if (bmc[(e + 0) / 3]) val.x = 0.f;
            if (bmc[(e + 1) / 3]) val.y = 0.f;
            if (bmc[(e + 2) / 3]) val.z = 0.f;
            if (bmc[(e + 3) / 3]) val.w = 0.f;
        }
        oi = cview * b0 + t;
    } else if (q < b1) {                         // covs, s=9
        int t = q - b0, e = 4 * t;
        val = __builtin_nontemporal_load(&covs4[cview * 9 * H4 + t]);
        if (has) {
            if (bmc[(e + 0) / 9]) val.x = 0.f;
            if (bmc[(e + 1) / 9]) val.y = 0.f;
            if (bmc[(e + 2) / 9]) val.z = 0.f;
            if (bmc[(e + 3) / 9]) val.w = 0.f;
        }
        oi = 3 * n4 + cview * 9 * H4 + t;
    } else if (q < b2) {                         // sh, s=75
        int t = q - b1, e = 4 * t;
        val = __builtin_nontemporal_load(&shs4[cview * 75 * H4 + t]);
        if (has) {
            if (bmc[(e + 0) / 75]) val.x = 0.f;
            if (bmc[(e + 1) / 75]) val.y = 0.f;
            if (bmc[(e + 2) / 75]) val.z = 0.f;
            if (bmc[(e + 3) / 75]) val.w = 0.f;
        }
        oi = 12 * n4 + cview * 75 * H4 + t;
    } else if (q < b3) {                         // opacity, s=1
        int t = q - b2, e = 4 * t;
        val = __builtin_nontemporal_load(&opas4[cview * H4 + t]);
        if (has) {
            if (bmc[e + 0]) val.x = 0.f;
            if (bmc[e + 1]) val.y = 0.f;
            if (bmc[e + 2]) val.z = 0.f;
            if (bmc[e + 3]) val.w = 0.f;
        }
        oi = 87 * n4 + cview * H4 + t;
    } else if (q < b4) {                         // scales, s=3
        int t = q - b3, e = 4 * t;
        val = __builtin_nontemporal_load(&scales4[cview * 3 * H4 + t]);
        if (has) {
            if (bmc[(e + 0) / 3]) val.x = 0.f;
            if (bmc[(e + 1) / 3]) val.y = 0.f;
            if (bmc[(e + 2) / 3]) val.z = 0.f;
            if (bmc[(e + 3) / 3]) val.w = 0.f;
        }
        oi = 88 * n4 + cview * 3 * H4 + t;
    } else if (q < b5) {                         // rots, s=4 -> one point/float4
        int t = q - b4;
        val = __builtin_nontemporal_load(&rots4[cview * 4 * H4 + t]);
        if (has && bmc[t]) { val.x = 0.f; val.y = 0.f; val.z = 0.f; val.w = 0.f; }
        oi = 91 * n4 + cview * 4 * H4 + t;
    } else {                                     // valid, s=1
        int t = q - b5, e = 4 * t;
        if (has) {
            val.x = bmc[e + 0] ? 0.f : 1.f;
            val.y = bmc[e + 1] ? 0.f : 1.f;
            val.z = bmc[e + 2] ? 0.f : 1.f;
            val.w = bmc[e + 3] ? 0.f : 1.f;
        } else {
            val.x = 1.f; val.y = 1.f; val.z = 1.f; val.w = 1.f;
        }
        oi = 95 * n4 + cview * H4 + t;
    }
    __builtin_nontemporal_store(val, &out[oi]);
}

extern "C" void kernel_launch(void* const* d_in, const int* in_sizes, int n_in,
                              void* d_out, int out_size, void* d_ws, size_t ws_size,
                              hipStream_t stream) {
    const float* means  = (const float*)d_in[0];
    const float* covs   = (const float*)d_in[1];
    const float* shs    = (const float*)d_in[2];
    const float* opas   = (const float*)d_in[3];
    const float* scales = (const float*)d_in[4];
    const float* rots   = (const float*)d_in[5];
    const float* extr   = (const float*)d_in[6];
    const float* intr   = (const float*)d_in[7];
    const int*   hp     = (const int*)d_in[8];
    const int*   wp     = (const int*)d_in[9];

    const int v  = in_sizes[6] / 16;      // b*v, b==1 here
    const int hw = in_sizes[3] / v;
    const long N = (long)v * hw;

    float*   w2c     = (float*)d_ws;                 // v*16 floats
    uint8_t* bitmaps = (uint8_t*)d_ws + 1024;        // v*hw bytes (region 0 unused)

    const int n4 = (int)(N >> 2);
    const int H4 = hw >> 2;
    const int c6 = 96 * H4;
    const int copy_blocks = (c6 + 255) / 256;

    if (v > 1) {   // zero bitmap regions 1..v-1 + invert extrinsics
        int n_words = (v - 1) * hw / 4;
        int blocks = (n_words + 255) / 256;
        init_kernel<<<blocks, 256, 0, stream>>>(extr, w2c,
                                                (uint32_t*)(bitmaps + hw), v, n_words);
    }

    // Mark view k (blocks first, latency-bound) || copy view k-1 (BW-bound).
    for (int view = 1; view < v; ++view) {
        int n_prev = view * hw;
        int mb = (n_prev + 255) / 256;
        int cv = view - 1;
        const uint8_t* bmc = (cv == 0) ? nullptr : bitmaps + (long)cv * hw;
        mark_copy<<<mb + copy_blocks, 256, 0, stream>>>(
            means, bitmaps, means + (long)view * hw * 3,
            w2c + view * 16, intr + view * 9, bitmaps + (long)view * hw,
            n_prev, hp, wp, hw, mb,
            (const f4*)means, (const f4*)covs, (const f4*)shs,
            (const f4*)opas, (const f4*)scales, (const f4*)rots,
            bmc, (f4*)d_out, cv, n4);
    }

    // Final copy: last view's slice (mask from its bitmap; no marking role).
    {
        int cv = v - 1;
        const uint8_t* bmc = (cv == 0) ? nullptr : bitmaps + (long)cv * hw;
        mark_copy<<<copy_blocks, 256, 0, stream>>>(
            means, bitmaps, means, w2c, intr, bitmaps,
            0, hp, wp, hw, 0,
            (const f4*)means, (const f4*)covs, (const f4*)shs,
            (const f4*)opas, (const f4*)scales, (const f4*)rots,
            bmc, (f4*)d_out, cv, n4);
    }
}